// Round 18
// baseline (377.590 us; speedup 1.0000x reference)
//
#include <hip/hip_runtime.h>

#define DF  128
#define NB  128    // hist blocks (chunked LDS hists)
#define ME  20000  // m (python scalar; fixed problem constant)
#define EW  10000  // e-hist packed words (2 keys/word)
#define VW  16667  // v-hist packed words per pass (covers 33334 keys)
#define VP  3      // v passes (3*33334 >= 100000)
#define VSPAN (2 * VW)
#define WINB 256   // scatter windows over pair space
#define WSH  13    // window = 8192 pair entries = 32 KB
#define RPB  16384 // records per block (2 * epb)

typedef float f32x2 __attribute__((ext_vector_type(2)));
typedef unsigned long long ull;

__device__ __forceinline__ unsigned bf16rne(float f) {
    unsigned u = __float_as_uint(f);
    return (u + 0x7fffu + ((u >> 16) & 1u)) >> 16;
}

// weight <-> 15-bit float (e5 biased at 96, m10). data in [0,1) -> exact fit.
__device__ __forceinline__ unsigned w15enc(float f) {
    unsigned bits = __float_as_uint(f);
    unsigned r = (bits + 0xFFFu + ((bits >> 13) & 1u)) >> 13;   // RNE
    return (r > (96u << 10)) ? (r - (96u << 10)) : 0u;
}
__device__ __forceinline__ float w15dec(unsigned w) {
    return w ? __uint_as_float((w + (96u << 10)) << 13) : 0.f;
}

// packed-bf16 dot2: acc += a.lo*b.lo + a.hi*b.hi
#if __has_builtin(__builtin_amdgcn_fdot2_f32_bf16)
typedef __bf16 bf16x2 __attribute__((ext_vector_type(2)));
__device__ __forceinline__ float dot2bf(unsigned a, unsigned b, float c) {
    return __builtin_amdgcn_fdot2_f32_bf16(
        __builtin_bit_cast(bf16x2, a), __builtin_bit_cast(bf16x2, b), c, false);
}
#else
__device__ __forceinline__ float dot2bf(unsigned a, unsigned b, float c) {
    c += __uint_as_float(a << 16) * __uint_as_float(b << 16);
    c += __uint_as_float(a & 0xffff0000u) * __uint_as_float(b & 0xffff0000u);
    return c;
}
#endif

// ================= H1: all-LDS histograms + BOTH rank captures ==============
__global__ __launch_bounds__(256) void hist_lds(
    const int* __restrict__ vi, const int* __restrict__ ei,
    unsigned short* __restrict__ rankE, unsigned short* __restrict__ rankV,
    unsigned* __restrict__ bhE, unsigned* __restrict__ bhV, int nnz, int epb)
{
    __shared__ unsigned lh[VW];   // 66.7 KB; e-phase uses first EW words
    int b = blockIdx.x;
    int lo = b * epb;
    int hi = min(nnz, lo + epb);
    int iters = epb >> 10;        // epb multiple of 1024

    // ---- e phase ----
    for (int w = threadIdx.x; w < EW; w += 256) lh[w] = 0;
    __syncthreads();
    for (int it = 0; it < iters; ++it) {
        int i = lo + (it * 256 + threadIdx.x) * 4;
        if (i + 4 <= hi) {
            int4 e4 = *(const int4*)(ei + i);
            int ee[4] = {e4.x, e4.y, e4.z, e4.w};
            unsigned short r[4];
            #pragma unroll
            for (int q = 0; q < 4; ++q) {
                int sh = (ee[q] & 1) * 16;
                unsigned ret = atomicAdd(&lh[ee[q] >> 1], 1u << sh);
                r[q] = (unsigned short)((ret >> sh) & 0xffffu);
            }
            *(ushort4*)(rankE + i) = ushort4{r[0], r[1], r[2], r[3]};
        } else {
            for (int j = i; j < hi; ++j) {
                int e = ei[j]; int sh = (e & 1) * 16;
                unsigned ret = atomicAdd(&lh[e >> 1], 1u << sh);
                rankE[j] = (unsigned short)((ret >> sh) & 0xffffu);
            }
        }
    }
    __syncthreads();
    for (int w = threadIdx.x; w < EW; w += 256)
        bhE[(size_t)b * EW + w] = lh[w];

    // ---- v passes (counts + rank capture) ----
    for (int p = 0; p < VP; ++p) {
        int vbase = p * VSPAN;
        __syncthreads();
        for (int w = threadIdx.x; w < VW; w += 256) lh[w] = 0;
        __syncthreads();
        for (int it = 0; it < iters; ++it) {
            int i = lo + (it * 256 + threadIdx.x) * 4;
            if (i + 4 <= hi) {
                int4 v4 = *(const int4*)(vi + i);
                int vv[4] = {v4.x, v4.y, v4.z, v4.w};
                #pragma unroll
                for (int q = 0; q < 4; ++q) {
                    int d = vv[q] - vbase;
                    if (d >= 0 && d < VSPAN) {
                        int sh = (d & 1) * 16;
                        unsigned ret = atomicAdd(&lh[d >> 1], 1u << sh);
                        rankV[i + q] = (unsigned short)((ret >> sh) & 0xffffu);
                    }
                }
            } else {
                for (int j = i; j < hi; ++j) {
                    int d = vi[j] - vbase;
                    if (d >= 0 && d < VSPAN) {
                        int sh = (d & 1) * 16;
                        unsigned ret = atomicAdd(&lh[d >> 1], 1u << sh);
                        rankV[j] = (unsigned short)((ret >> sh) & 0xffffu);
                    }
                }
            }
        }
        __syncthreads();
        for (int w = threadIdx.x; w < VW; w += 256)
            bhV[(size_t)b * (VP * VW) + p * VW + w] = lh[w];
    }
}

// ===== S1: column scans (hist->bases, packed, BOTH sides) + conversions =====
__global__ __launch_bounds__(256) void scan_cols_conv(
    unsigned* __restrict__ bhE, unsigned* __restrict__ bhV,
    int* __restrict__ totE, int* __restrict__ totV,
    const float* __restrict__ nf, const float* __restrict__ W,
    unsigned* __restrict__ nfh, unsigned* __restrict__ wp, int n, int n64)
{
    int tid = blockIdx.x * 256 + threadIdx.x;
    if (tid < EW) {
        unsigned run0 = 0, run1 = 0;
        #pragma unroll 4
        for (int b = 0; b < NB; ++b) {
            unsigned w = bhE[(size_t)b * EW + tid];
            bhE[(size_t)b * EW + tid] = run0 | (run1 << 16);   // exclusive bases
            run0 += w & 0xffffu; run1 += w >> 16;
        }
        totE[2 * tid] = (int)run0;
        totE[2 * tid + 1] = (int)run1;
    } else if (tid < EW + VP * VW) {
        int w = tid - EW;                    // word in [0, VP*VW)
        unsigned run0 = 0, run1 = 0;
        #pragma unroll 4
        for (int b = 0; b < NB; ++b) {
            unsigned x = bhV[(size_t)b * (VP * VW) + w];
            bhV[(size_t)b * (VP * VW) + w] = run0 | (run1 << 16);  // bases
            run0 += x & 0xffffu; run1 += x >> 16;
        }
        int p = w / VW, wi = w - p * VW;
        int k0 = p * VSPAN + 2 * wi;
        if (k0 < n) totV[k0] = (int)run0;
        if (k0 + 1 < n) totV[k0 + 1] = (int)run1;
    }
    // ---- conversions (grid-stride) ----
    int nth = gridDim.x * 256;
    const float2* __restrict__ in2 = (const float2*)nf;
    for (int i = tid; i < n64; i += nth) {
        float2 f = in2[i];
        nfh[i] = bf16rne(f.x) | (bf16rne(f.y) << 16);
    }
    if (tid < DF * 64) {
        int j = tid >> 6, k2 = tid & 63;
        float2 f = ((const float2*)W)[tid];
        wp[k2 * DF + j] = bf16rne(f.x) | (bf16rne(f.y) << 16);
    }
}

// ================= scans: exclusive prefix over [totE | totV] ===============
__global__ __launch_bounds__(256) void scan_k1(
    const int* __restrict__ totE, const int* __restrict__ totV,
    int* __restrict__ bsum, int m, int len)
{
    __shared__ int s[256];
    int tid = threadIdx.x;
    int base = blockIdx.x * 2048 + tid * 8;
    int t = 0;
    #pragma unroll
    for (int i = 0; i < 8; ++i) {
        int idx = base + i;
        if (idx < len) t += (idx < m) ? totE[idx] : totV[idx - m];
    }
    s[tid] = t; __syncthreads();
    for (int d = 128; d > 0; d >>= 1) {
        if (tid < d) s[tid] += s[tid + d];
        __syncthreads();
    }
    if (tid == 0) bsum[blockIdx.x] = s[0];
}

__global__ __launch_bounds__(256) void scan_k2(int* __restrict__ bsum, int nb)
{
    __shared__ int s[256];
    int t = threadIdx.x;
    int v = (t < nb) ? bsum[t] : 0;
    s[t] = v; __syncthreads();
    for (int d = 1; d < 256; d <<= 1) {
        int u = (t >= d) ? s[t - d] : 0;
        __syncthreads();
        s[t] += u;
        __syncthreads();
    }
    if (t < nb) bsum[t] = s[t] - v;   // exclusive
}

__global__ __launch_bounds__(256) void scan_k3(
    const int* __restrict__ totE, const int* __restrict__ totV,
    const int* __restrict__ bsum, int* __restrict__ seg, int m, int len)
{
    __shared__ int s[256];
    int tid = threadIdx.x;
    int base = blockIdx.x * 2048 + tid * 8;
    int v[8]; int t = 0;
    #pragma unroll
    for (int i = 0; i < 8; ++i) {
        int idx = base + i;
        v[i] = (idx < len) ? ((idx < m) ? totE[idx] : totV[idx - m]) : 0;
        t += v[i];
    }
    s[tid] = t; __syncthreads();
    for (int d = 1; d < 256; d <<= 1) {
        int u = (tid >= d) ? s[tid - d] : 0;
        __syncthreads();
        s[tid] += u;
        __syncthreads();
    }
    int run = bsum[blockIdx.x] + (s[tid] - t);
    #pragma unroll
    for (int i = 0; i < 8; ++i) {
        int idx = base + i;
        if (idx < len) { seg[idx] = run; run += v[i]; }
    }
}

// ======= position helper (shared by both place_a sweeps; deterministic) =====
__device__ __forceinline__ void edge_pos(
    int i, int e, int v, const int* __restrict__ seg,
    const unsigned* __restrict__ be, const unsigned* __restrict__ bv,
    const unsigned short* __restrict__ rankE,
    const unsigned short* __restrict__ rankV,
    int m, int* pe, int* pv)
{
    unsigned bwE = be[e >> 1];
    int baseE = (int)((bwE >> ((e & 1) * 16)) & 0xffffu);
    int p = v / VSPAN;
    int d = v - p * VSPAN;
    unsigned bwV = bv[p * VW + (d >> 1)];
    int baseV = (int)((bwV >> ((d & 1) * 16)) & 0xffffu);
    *pe = seg[e] + baseE + rankE[i];
    *pv = seg[m + v] + baseV + rankV[i];
}

// ===== place pass A: bin records by destination window, dense staging =======
__global__ __launch_bounds__(256) void place_a(
    const int* __restrict__ vi, const int* __restrict__ ei,
    const float* __restrict__ data,
    const unsigned short* __restrict__ rankE,
    const unsigned short* __restrict__ rankV,
    const int* __restrict__ seg,
    const unsigned* __restrict__ bhE, const unsigned* __restrict__ bhV,
    ull* __restrict__ stage, unsigned* __restrict__ tstart,
    unsigned* __restrict__ tcnt, int nnz, int m, int epb)
{
    __shared__ unsigned cnt[WINB];
    __shared__ unsigned off[WINB];
    __shared__ unsigned s[WINB];
    int b = blockIdx.x;
    int lo = b * epb;
    int hi = min(nnz, lo + epb);
    const unsigned* __restrict__ be = bhE + (size_t)b * EW;
    const unsigned* __restrict__ bv = bhV + (size_t)b * (VP * VW);

    for (int w = threadIdx.x; w < WINB; w += 256) cnt[w] = 0;
    __syncthreads();

    // sweep 1: count records per window
    for (int i = lo + threadIdx.x; i < hi; i += 256) {
        int e = ei[i], v = vi[i], pe, pv;
        edge_pos(i, e, v, seg, be, bv, rankE, rankV, m, &pe, &pv);
        atomicAdd(&cnt[pe >> WSH], 1u);
        atomicAdd(&cnt[pv >> WSH], 1u);
    }
    __syncthreads();

    // exclusive prefix over cnt; publish table
    int t = threadIdx.x;
    unsigned c = cnt[t];
    tcnt[(size_t)b * WINB + t] = c;
    s[t] = c; __syncthreads();
    for (int d = 1; d < 256; d <<= 1) {
        unsigned u = (t >= d) ? s[t - d] : 0;
        __syncthreads();
        s[t] += u;
        __syncthreads();
    }
    off[t] = s[t] - c;
    tstart[(size_t)b * WINB + t] = s[t] - c;
    __syncthreads();

    // sweep 2: recompute positions, stage {pos,payload} densely per bin
    ull* __restrict__ sb = stage + (size_t)b * RPB;
    for (int i = lo + threadIdx.x; i < hi; i += 256) {
        int e = ei[i], v = vi[i], pe, pv;
        edge_pos(i, e, v, seg, be, bv, rankE, rankV, m, &pe, &pv);
        unsigned w15 = w15enc(data[i]) << 17;
        unsigned oe = atomicAdd(&off[pe >> WSH], 1u);
        sb[oe] = ((ull)(unsigned)pe << 32) | (w15 | (unsigned)v);
        unsigned ov = atomicAdd(&off[pv >> WSH], 1u);
        sb[ov] = ((ull)(unsigned)pv << 32) | (w15 | (unsigned)e);
    }
}

// ===== place pass B: one WG per window; scattered stores stay L2-resident ===
__global__ __launch_bounds__(256) void place_b(
    const ull* __restrict__ stage, const unsigned* __restrict__ tstart,
    const unsigned* __restrict__ tcnt, unsigned* __restrict__ pair)
{
    int w = blockIdx.x;
    for (int b = 0; b < NB; ++b) {
        unsigned st = tstart[(size_t)b * WINB + w];
        unsigned c  = tcnt[(size_t)b * WINB + w];
        const ull* __restrict__ src = stage + (size_t)b * RPB + st;
        for (unsigned r = threadIdx.x; r < c; r += 256) {
            ull rec = __builtin_nontemporal_load(src + r);
            pair[(unsigned)(rec >> 32)] = (unsigned)rec;
        }
    }
}

// ======== fused gather_y + linear: e16[s] = bf16( (d_e>0) ? yrow@W^T+b : 0 ) =
__global__ __launch_bounds__(256) void gather_y_linear(
    const unsigned* __restrict__ nfh, const int* __restrict__ seg,
    const unsigned* __restrict__ pair, const unsigned* __restrict__ wp,
    const float* __restrict__ b, unsigned* __restrict__ e16, int m)
{
    __shared__ unsigned rowbuf[4][64];
    int wv = threadIdx.x >> 6;
    int wid = (blockIdx.x * 256 + threadIdx.x) >> 6;
    int lane = threadIdx.x & 63;
    if (wid >= m) return;
    int start = seg[wid];
    int end   = seg[wid + 1];      // seg[m] == nnz (start of v-CSR); never mutated
    float ax = 0.f, ay = 0.f, ws = 0.f;
    int k = start;
    for (; k + 16 <= end; k += 16) {
        unsigned p[16];
        #pragma unroll
        for (int q = 0; q < 16; ++q) p[q] = __builtin_nontemporal_load(pair + k + q);
        unsigned u[16];
        #pragma unroll
        for (int q = 0; q < 16; ++q) u[q] = nfh[(size_t)(p[q] & 0x1FFFFu) * 64 + lane];
        #pragma unroll
        for (int q = 0; q < 16; ++q) {
            float w = w15dec(p[q] >> 17);
            ax += w * __uint_as_float(u[q] << 16);
            ay += w * __uint_as_float(u[q] & 0xffff0000u);
            ws += w;
        }
    }
    for (; k + 4 <= end; k += 4) {
        unsigned p[4];
        #pragma unroll
        for (int q = 0; q < 4; ++q) p[q] = __builtin_nontemporal_load(pair + k + q);
        unsigned u[4];
        #pragma unroll
        for (int q = 0; q < 4; ++q) u[q] = nfh[(size_t)(p[q] & 0x1FFFFu) * 64 + lane];
        #pragma unroll
        for (int q = 0; q < 4; ++q) {
            float w = w15dec(p[q] >> 17);
            ax += w * __uint_as_float(u[q] << 16);
            ay += w * __uint_as_float(u[q] & 0xffff0000u);
            ws += w;
        }
    }
    for (; k < end; ++k) {
        unsigned p0 = __builtin_nontemporal_load(pair + k);
        float w0 = w15dec(p0 >> 17);
        unsigned ua = nfh[(size_t)(p0 & 0x1FFFFu) * 64 + lane];
        ax += w0 * __uint_as_float(ua << 16);
        ay += w0 * __uint_as_float(ua & 0xffff0000u);
        ws += w0;
    }
    float inv = (ws > 0.f) ? 1.f / ws : 0.f;
    rowbuf[wv][lane] = bf16rne(ax * inv) | (bf16rne(ay * inv) << 16);
    // wave-private LDS region: in-wave ds ordering suffices, no barrier.

    float2 bb = ((const float2*)b)[lane];
    float acc0 = (ws > 0.f) ? bb.x : 0.f;
    float acc1 = (ws > 0.f) ? bb.y : 0.f;
    const unsigned* __restrict__ row = rowbuf[wv];
    #pragma unroll 8
    for (int k2 = 0; k2 < 64; ++k2) {
        unsigned r = row[k2];                         // broadcast (y[2k2],y[2k2+1])
        uint2 u = ((const uint2*)(wp + k2 * DF))[lane];
        acc0 = dot2bf(r, u.x, acc0);
        acc1 = dot2bf(r, u.y, acc1);
    }
    e16[(size_t)wid * 64 + lane] = bf16rne(acc0) | (bf16rne(acc1) << 16);
}

// ================= gather_out: out[v] = segsum(w*e16[eidx]) / d_v ===========
__global__ __launch_bounds__(256) void gather_out(
    const unsigned* __restrict__ e16, const int* __restrict__ seg,
    const unsigned* __restrict__ pair,
    float* __restrict__ out, int n, int m, int tot)
{
    int wid = (blockIdx.x * 256 + threadIdx.x) >> 6;
    int lane = threadIdx.x & 63;
    if (wid >= n) return;
    int idx = m + wid;
    int start = seg[idx];
    int end   = (wid == n - 1) ? tot : seg[idx + 1];
    float ax = 0.f, ay = 0.f, ws = 0.f;
    int k = start;
    for (; k + 16 <= end; k += 16) {
        unsigned p[16];
        #pragma unroll
        for (int q = 0; q < 16; ++q) p[q] = __builtin_nontemporal_load(pair + k + q);
        unsigned u[16];
        #pragma unroll
        for (int q = 0; q < 16; ++q) u[q] = e16[(size_t)(p[q] & 0x1FFFFu) * 64 + lane];
        #pragma unroll
        for (int q = 0; q < 16; ++q) {
            float w = w15dec(p[q] >> 17);
            ax += w * __uint_as_float(u[q] << 16);
            ay += w * __uint_as_float(u[q] & 0xffff0000u);
            ws += w;
        }
    }
    for (; k + 4 <= end; k += 4) {
        unsigned p[4];
        #pragma unroll
        for (int q = 0; q < 4; ++q) p[q] = __builtin_nontemporal_load(pair + k + q);
        unsigned u[4];
        #pragma unroll
        for (int q = 0; q < 4; ++q) u[q] = e16[(size_t)(p[q] & 0x1FFFFu) * 64 + lane];
        #pragma unroll
        for (int q = 0; q < 4; ++q) {
            float w = w15dec(p[q] >> 17);
            ax += w * __uint_as_float(u[q] << 16);
            ay += w * __uint_as_float(u[q] & 0xffff0000u);
            ws += w;
        }
    }
    for (; k < end; ++k) {
        unsigned p0 = __builtin_nontemporal_load(pair + k);
        float w0 = w15dec(p0 >> 17);
        unsigned ua = e16[(size_t)(p0 & 0x1FFFFu) * 64 + lane];
        ax += w0 * __uint_as_float(ua << 16);
        ay += w0 * __uint_as_float(ua & 0xffff0000u);
        ws += w0;
    }
    float inv = (ws > 0.f) ? 1.f / ws : 0.f;
    f32x2 o = {ax * inv, ay * inv};
    __builtin_nontemporal_store(o, (f32x2*)out + (size_t)wid * 64 + lane);
}

extern "C" void kernel_launch(void* const* d_in, const int* in_sizes, int n_in,
                              void* d_out, int out_size, void* d_ws, size_t ws_size,
                              hipStream_t stream)
{
    const float* nf   = (const float*)d_in[0];
    const float* data = (const float*)d_in[1];
    const float* W    = (const float*)d_in[2];
    const float* b    = (const float*)d_in[3];
    const int*   vi   = (const int*)d_in[4];
    const int*   ei   = (const int*)d_in[5];

    const int n   = in_sizes[0] / DF;   // 100000
    const int nnz = in_sizes[1];        // 1000000
    const int m   = ME;                 // 20000

    // epb: multiple of 1024 so each block's quad loop is exact & 16B-aligned
    const int epb = ((nnz + NB - 1) / NB + 1023) & ~1023;   // 8192 for 1M

    // -------- workspace layout (~70.7 MB; e16 aliases the dead ranks) ------
    int*   seg   = (int*)d_ws;                  // [m+n] starts (never mutated)
    int*   bsum  = seg + (m + n);               // [256]
    int*   totE  = bsum + 256;                  // [m]
    int*   totV  = totE + m;                    // [n]
    // alias region: ranks (4 MB, dead after place) / e16 (5.12 MB, born after)
    unsigned short* rankE = (unsigned short*)(totV + n);   // [nnz] u16
    unsigned short* rankV = rankE + nnz;                   // [nnz] u16
    unsigned* e16 = (unsigned*)rankE;                      // [m*64] (alias)
    unsigned* pair = (unsigned*)rankE + ((size_t)m * 64 > (size_t)nnz ?
                     (size_t)m * 64 : (size_t)nnz);        // after max(e16,ranks)
    unsigned* wp  = pair + 2 * (size_t)nnz;     // [DF*64]
    unsigned* nfh = wp + DF * 64;               // [n*64]
    unsigned* bhE = nfh + (size_t)n * 64;       // [NB*EW] packed counts->bases
    unsigned* bhV = bhE + (size_t)NB * EW;      // [NB*VP*VW] packed counts->bases
    unsigned* tstart = bhV + (size_t)NB * (VP * VW);  // [NB*WINB]
    unsigned* tcnt   = tstart + (size_t)NB * WINB;    // [NB*WINB]
    float* out   = (float*)d_out;
    // d_out doubles as dense record staging for place (16 MB of 51.2 MB);
    // gather_out later overwrites every element of d_out.
    ull* stage = (ull*)d_out;

    hist_lds<<<NB, 256, 0, stream>>>(vi, ei, rankE, rankV, bhE, bhV, nnz, epb);

    scan_cols_conv<<<512, 256, 0, stream>>>(bhE, bhV, totE, totV,
                                            nf, W, nfh, wp, n, n * 64);

    int len = m + n;
    int nb = (len + 2047) / 2048;
    scan_k1<<<nb, 256, 0, stream>>>(totE, totV, bsum, m, len);
    scan_k2<<<1, 256, 0, stream>>>(bsum, nb);
    scan_k3<<<nb, 256, 0, stream>>>(totE, totV, bsum, seg, m, len);

    place_a<<<NB, 256, 0, stream>>>(vi, ei, data, rankE, rankV, seg,
                                    bhE, bhV, stage, tstart, tcnt, nnz, m, epb);
    place_b<<<WINB, 256, 0, stream>>>(stage, tstart, tcnt, pair);

    gather_y_linear<<<(m + 3) / 4, 256, 0, stream>>>(nfh, seg, pair, wp, b, e16, m);
    gather_out<<<(n + 3) / 4, 256, 0, stream>>>(e16, seg, pair, out, n, m, 2 * nnz);
}

// Round 19
// 263.889 us; speedup vs baseline: 1.4309x; 1.4309x over previous
//
#include <hip/hip_runtime.h>

#define DF  128
#define NB  128    // hist blocks (chunked LDS hists)
#define ME  20000  // m (python scalar; fixed problem constant)
#define EW  10000  // e-hist packed words (2 keys/word)
#define VW  25000  // v-hist packed words per pass (covers 50000 keys, 100KB LDS)
#define VP  2      // v passes (2*50000 == 100000 == n)
#define VSPAN (2 * VW)

typedef float f32x2 __attribute__((ext_vector_type(2)));

__device__ __forceinline__ unsigned bf16rne(float f) {
    unsigned u = __float_as_uint(f);
    return (u + 0x7fffu + ((u >> 16) & 1u)) >> 16;
}

// weight <-> 15-bit float (e5 biased at 96, m10). data in [0,1) -> exact fit.
__device__ __forceinline__ unsigned w15enc(float f) {
    unsigned bits = __float_as_uint(f);
    unsigned r = (bits + 0xFFFu + ((bits >> 13) & 1u)) >> 13;   // RNE
    return (r > (96u << 10)) ? (r - (96u << 10)) : 0u;
}
__device__ __forceinline__ float w15dec(unsigned w) {
    return w ? __uint_as_float((w + (96u << 10)) << 13) : 0.f;
}

// packed-bf16 dot2: acc += a.lo*b.lo + a.hi*b.hi
#if __has_builtin(__builtin_amdgcn_fdot2_f32_bf16)
typedef __bf16 bf16x2 __attribute__((ext_vector_type(2)));
__device__ __forceinline__ float dot2bf(unsigned a, unsigned b, float c) {
    return __builtin_amdgcn_fdot2_f32_bf16(
        __builtin_bit_cast(bf16x2, a), __builtin_bit_cast(bf16x2, b), c, false);
}
#else
__device__ __forceinline__ float dot2bf(unsigned a, unsigned b, float c) {
    c += __uint_as_float(a << 16) * __uint_as_float(b << 16);
    c += __uint_as_float(a & 0xffff0000u) * __uint_as_float(b & 0xffff0000u);
    return c;
}
#endif

// ================= H1: all-LDS histograms + BOTH rank captures ==============
// e: packed 2-keys/word LDS hist, rankE = packed atomic return (u16).
// v: 2 range passes (100KB LDS window); rankV captured from the LDS atomic
// return (each edge falls in exactly one pass). ZERO global atomics anywhere.
__global__ __launch_bounds__(256) void hist_lds(
    const int* __restrict__ vi, const int* __restrict__ ei,
    unsigned short* __restrict__ rankE, unsigned short* __restrict__ rankV,
    unsigned* __restrict__ bhE, unsigned* __restrict__ bhV, int nnz, int epb)
{
    __shared__ unsigned lh[VW];   // 100 KB; e-phase uses first EW words
    int b = blockIdx.x;
    int lo = b * epb;
    int hi = min(nnz, lo + epb);
    int iters = epb >> 10;        // epb multiple of 1024

    // ---- e phase ----
    for (int w = threadIdx.x; w < EW; w += 256) lh[w] = 0;
    __syncthreads();
    for (int it = 0; it < iters; ++it) {
        int i = lo + (it * 256 + threadIdx.x) * 4;
        if (i + 4 <= hi) {
            int4 e4 = *(const int4*)(ei + i);
            int ee[4] = {e4.x, e4.y, e4.z, e4.w};
            unsigned short r[4];
            #pragma unroll
            for (int q = 0; q < 4; ++q) {
                int sh = (ee[q] & 1) * 16;
                unsigned ret = atomicAdd(&lh[ee[q] >> 1], 1u << sh);
                r[q] = (unsigned short)((ret >> sh) & 0xffffu);
            }
            *(ushort4*)(rankE + i) = ushort4{r[0], r[1], r[2], r[3]};
        } else {
            for (int j = i; j < hi; ++j) {
                int e = ei[j]; int sh = (e & 1) * 16;
                unsigned ret = atomicAdd(&lh[e >> 1], 1u << sh);
                rankE[j] = (unsigned short)((ret >> sh) & 0xffffu);
            }
        }
    }
    __syncthreads();
    for (int w = threadIdx.x; w < EW; w += 256)
        bhE[(size_t)b * EW + w] = lh[w];

    // ---- v passes (counts + rank capture) ----
    for (int p = 0; p < VP; ++p) {
        int vbase = p * VSPAN;
        __syncthreads();
        for (int w = threadIdx.x; w < VW; w += 256) lh[w] = 0;
        __syncthreads();
        for (int it = 0; it < iters; ++it) {
            int i = lo + (it * 256 + threadIdx.x) * 4;
            if (i + 4 <= hi) {
                int4 v4 = *(const int4*)(vi + i);
                int vv[4] = {v4.x, v4.y, v4.z, v4.w};
                #pragma unroll
                for (int q = 0; q < 4; ++q) {
                    int d = vv[q] - vbase;
                    if (d >= 0 && d < VSPAN) {
                        int sh = (d & 1) * 16;
                        unsigned ret = atomicAdd(&lh[d >> 1], 1u << sh);
                        rankV[i + q] = (unsigned short)((ret >> sh) & 0xffffu);
                    }
                }
            } else {
                for (int j = i; j < hi; ++j) {
                    int d = vi[j] - vbase;
                    if (d >= 0 && d < VSPAN) {
                        int sh = (d & 1) * 16;
                        unsigned ret = atomicAdd(&lh[d >> 1], 1u << sh);
                        rankV[j] = (unsigned short)((ret >> sh) & 0xffffu);
                    }
                }
            }
        }
        __syncthreads();
        for (int w = threadIdx.x; w < VW; w += 256)
            bhV[(size_t)b * (VP * VW) + p * VW + w] = lh[w];
    }
}

// ===== S1: column scans (hist->bases, packed, BOTH sides) + conversions =====
__global__ __launch_bounds__(256) void scan_cols_conv(
    unsigned* __restrict__ bhE, unsigned* __restrict__ bhV,
    int* __restrict__ totE, int* __restrict__ totV,
    const float* __restrict__ nf, const float* __restrict__ W,
    unsigned* __restrict__ nfh, unsigned* __restrict__ wp, int n, int n64)
{
    int tid = blockIdx.x * 256 + threadIdx.x;
    if (tid < EW) {
        unsigned run0 = 0, run1 = 0;
        #pragma unroll 4
        for (int b = 0; b < NB; ++b) {
            unsigned w = bhE[(size_t)b * EW + tid];
            bhE[(size_t)b * EW + tid] = run0 | (run1 << 16);   // exclusive bases
            run0 += w & 0xffffu; run1 += w >> 16;
        }
        totE[2 * tid] = (int)run0;
        totE[2 * tid + 1] = (int)run1;
    } else if (tid < EW + VP * VW) {
        int w = tid - EW;                    // word in [0, VP*VW)
        unsigned run0 = 0, run1 = 0;
        #pragma unroll 4
        for (int b = 0; b < NB; ++b) {
            unsigned x = bhV[(size_t)b * (VP * VW) + w];
            bhV[(size_t)b * (VP * VW) + w] = run0 | (run1 << 16);  // bases
            run0 += x & 0xffffu; run1 += x >> 16;
        }
        int p = w / VW, wi = w - p * VW;
        int k0 = p * VSPAN + 2 * wi;
        if (k0 < n) totV[k0] = (int)run0;
        if (k0 + 1 < n) totV[k0 + 1] = (int)run1;
    }
    // ---- conversions (grid-stride) ----
    int nth = gridDim.x * 256;
    const float2* __restrict__ in2 = (const float2*)nf;
    for (int i = tid; i < n64; i += nth) {
        float2 f = in2[i];
        nfh[i] = bf16rne(f.x) | (bf16rne(f.y) << 16);
    }
    if (tid < DF * 64) {
        int j = tid >> 6, k2 = tid & 63;
        float2 f = ((const float2*)W)[tid];
        wp[k2 * DF + j] = bf16rne(f.x) | (bf16rne(f.y) << 16);
    }
}

// ================= scans: exclusive prefix over [totE | totV] ===============
__global__ __launch_bounds__(256) void scan_k1(
    const int* __restrict__ totE, const int* __restrict__ totV,
    int* __restrict__ bsum, int m, int len)
{
    __shared__ int s[256];
    int tid = threadIdx.x;
    int base = blockIdx.x * 2048 + tid * 8;
    int t = 0;
    #pragma unroll
    for (int i = 0; i < 8; ++i) {
        int idx = base + i;
        if (idx < len) t += (idx < m) ? totE[idx] : totV[idx - m];
    }
    s[tid] = t; __syncthreads();
    for (int d = 128; d > 0; d >>= 1) {
        if (tid < d) s[tid] += s[tid + d];
        __syncthreads();
    }
    if (tid == 0) bsum[blockIdx.x] = s[0];
}

__global__ __launch_bounds__(256) void scan_k2(int* __restrict__ bsum, int nb)
{
    __shared__ int s[256];
    int t = threadIdx.x;
    int v = (t < nb) ? bsum[t] : 0;
    s[t] = v; __syncthreads();
    for (int d = 1; d < 256; d <<= 1) {
        int u = (t >= d) ? s[t - d] : 0;
        __syncthreads();
        s[t] += u;
        __syncthreads();
    }
    if (t < nb) bsum[t] = s[t] - v;   // exclusive
}

__global__ __launch_bounds__(256) void scan_k3(
    const int* __restrict__ totE, const int* __restrict__ totV,
    const int* __restrict__ bsum, int* __restrict__ seg, int m, int len)
{
    __shared__ int s[256];
    int tid = threadIdx.x;
    int base = blockIdx.x * 2048 + tid * 8;
    int v[8]; int t = 0;
    #pragma unroll
    for (int i = 0; i < 8; ++i) {
        int idx = base + i;
        v[i] = (idx < len) ? ((idx < m) ? totE[idx] : totV[idx - m]) : 0;
        t += v[i];
    }
    s[tid] = t; __syncthreads();
    for (int d = 1; d < 256; d <<= 1) {
        int u = (tid >= d) ? s[tid - d] : 0;
        __syncthreads();
        s[tid] += u;
        __syncthreads();
    }
    int run = bsum[blockIdx.x] + (s[tid] - t);
    #pragma unroll
    for (int i = 0; i < 8; ++i) {
        int idx = base + i;
        if (idx < len) { seg[idx] = run; run += v[i]; }
    }
}

// ============ placement: FULLY atomic-free scatter (both sides) =============
__global__ __launch_bounds__(256) void place_kernel(
    const int* __restrict__ vi, const int* __restrict__ ei,
    const float* __restrict__ data,
    const unsigned short* __restrict__ rankE,
    const unsigned short* __restrict__ rankV,
    const int* __restrict__ seg,
    const unsigned* __restrict__ bhE, const unsigned* __restrict__ bhV,
    unsigned* __restrict__ pair, int nnz, int m, int epb)
{
    int base = (blockIdx.x * 256 + threadIdx.x) * 4;
    if (base + 4 <= nnz) {
        int bH = base / epb;               // quad never straddles (epb %4==0)
        const unsigned* __restrict__ be = bhE + (size_t)bH * EW;
        const unsigned* __restrict__ bv = bhV + (size_t)bH * (VP * VW);
        int4 e4 = *(const int4*)(ei + base);
        int4 v4 = *(const int4*)(vi + base);
        ushort4 re4 = *(const ushort4*)(rankE + base);
        ushort4 rv4 = *(const ushort4*)(rankV + base);
        float4 d4 = *(const float4*)(data + base);
        int ee[4] = {e4.x, e4.y, e4.z, e4.w};
        int vv[4] = {v4.x, v4.y, v4.z, v4.w};
        unsigned short rre[4] = {re4.x, re4.y, re4.z, re4.w};
        unsigned short rrv[4] = {rv4.x, rv4.y, rv4.z, rv4.w};
        float dd[4] = {d4.x, d4.y, d4.z, d4.w};
        #pragma unroll
        for (int q = 0; q < 4; ++q) {
            unsigned w15 = w15enc(dd[q]) << 17;
            unsigned bwE = be[ee[q] >> 1];
            int baseE = (int)((bwE >> ((ee[q] & 1) * 16)) & 0xffffu);
            int p = vv[q] / VSPAN;
            int d = vv[q] - p * VSPAN;
            unsigned bwV = bv[p * VW + (d >> 1)];
            int baseV = (int)((bwV >> ((d & 1) * 16)) & 0xffffu);
            int pe = seg[ee[q]] + baseE + rre[q];
            int pv = seg[m + vv[q]] + baseV + rrv[q];
            __builtin_nontemporal_store(w15 | (unsigned)vv[q], pair + pe);
            __builtin_nontemporal_store(w15 | (unsigned)ee[q], pair + pv);
        }
    } else {
        for (int i = base; i < nnz; ++i) {
            int bH = i / epb;
            int e = ei[i], v = vi[i];
            unsigned w15 = w15enc(data[i]) << 17;
            unsigned bwE = bhE[(size_t)bH * EW + (e >> 1)];
            int baseE = (int)((bwE >> ((e & 1) * 16)) & 0xffffu);
            int p = v / VSPAN;
            int d = v - p * VSPAN;
            unsigned bwV = bhV[(size_t)bH * (VP * VW) + p * VW + (d >> 1)];
            int baseV = (int)((bwV >> ((d & 1) * 16)) & 0xffffu);
            int pe = seg[e] + baseE + rankE[i];
            int pv = seg[m + v] + baseV + rankV[i];
            __builtin_nontemporal_store(w15 | (unsigned)v, pair + pe);
            __builtin_nontemporal_store(w15 | (unsigned)e, pair + pv);
        }
    }
}

// ======== fused gather_y + linear: e16[s] = bf16( (d_e>0) ? yrow@W^T+b : 0 ) =
__global__ __launch_bounds__(256) void gather_y_linear(
    const unsigned* __restrict__ nfh, const int* __restrict__ seg,
    const unsigned* __restrict__ pair, const unsigned* __restrict__ wp,
    const float* __restrict__ b, unsigned* __restrict__ e16, int m)
{
    __shared__ unsigned rowbuf[4][64];
    int wv = threadIdx.x >> 6;
    int wid = (blockIdx.x * 256 + threadIdx.x) >> 6;
    int lane = threadIdx.x & 63;
    if (wid >= m) return;
    int start = seg[wid];
    int end   = seg[wid + 1];      // seg[m] == nnz (start of v-CSR); never mutated
    float ax = 0.f, ay = 0.f, ws = 0.f;
    int k = start;
    for (; k + 16 <= end; k += 16) {
        unsigned p[16];
        #pragma unroll
        for (int q = 0; q < 16; ++q) p[q] = __builtin_nontemporal_load(pair + k + q);
        unsigned u[16];
        #pragma unroll
        for (int q = 0; q < 16; ++q) u[q] = nfh[(size_t)(p[q] & 0x1FFFFu) * 64 + lane];
        #pragma unroll
        for (int q = 0; q < 16; ++q) {
            float w = w15dec(p[q] >> 17);
            ax += w * __uint_as_float(u[q] << 16);
            ay += w * __uint_as_float(u[q] & 0xffff0000u);
            ws += w;
        }
    }
    for (; k + 4 <= end; k += 4) {
        unsigned p[4];
        #pragma unroll
        for (int q = 0; q < 4; ++q) p[q] = __builtin_nontemporal_load(pair + k + q);
        unsigned u[4];
        #pragma unroll
        for (int q = 0; q < 4; ++q) u[q] = nfh[(size_t)(p[q] & 0x1FFFFu) * 64 + lane];
        #pragma unroll
        for (int q = 0; q < 4; ++q) {
            float w = w15dec(p[q] >> 17);
            ax += w * __uint_as_float(u[q] << 16);
            ay += w * __uint_as_float(u[q] & 0xffff0000u);
            ws += w;
        }
    }
    for (; k < end; ++k) {
        unsigned p0 = __builtin_nontemporal_load(pair + k);
        float w0 = w15dec(p0 >> 17);
        unsigned ua = nfh[(size_t)(p0 & 0x1FFFFu) * 64 + lane];
        ax += w0 * __uint_as_float(ua << 16);
        ay += w0 * __uint_as_float(ua & 0xffff0000u);
        ws += w0;
    }
    float inv = (ws > 0.f) ? 1.f / ws : 0.f;
    rowbuf[wv][lane] = bf16rne(ax * inv) | (bf16rne(ay * inv) << 16);
    // wave-private LDS region: in-wave ds ordering suffices, no barrier.

    float2 bb = ((const float2*)b)[lane];
    float acc0 = (ws > 0.f) ? bb.x : 0.f;
    float acc1 = (ws > 0.f) ? bb.y : 0.f;
    const unsigned* __restrict__ row = rowbuf[wv];
    #pragma unroll 8
    for (int k2 = 0; k2 < 64; ++k2) {
        unsigned r = row[k2];                         // broadcast (y[2k2],y[2k2+1])
        uint2 u = ((const uint2*)(wp + k2 * DF))[lane];
        acc0 = dot2bf(r, u.x, acc0);
        acc1 = dot2bf(r, u.y, acc1);
    }
    e16[(size_t)wid * 64 + lane] = bf16rne(acc0) | (bf16rne(acc1) << 16);
}

// ================= gather_out: out[v] = segsum(w*e16[eidx]) / d_v ===========
__global__ __launch_bounds__(256) void gather_out(
    const unsigned* __restrict__ e16, const int* __restrict__ seg,
    const unsigned* __restrict__ pair,
    float* __restrict__ out, int n, int m, int tot)
{
    int wid = (blockIdx.x * 256 + threadIdx.x) >> 6;
    int lane = threadIdx.x & 63;
    if (wid >= n) return;
    int idx = m + wid;
    int start = seg[idx];
    int end   = (wid == n - 1) ? tot : seg[idx + 1];
    float ax = 0.f, ay = 0.f, ws = 0.f;
    int k = start;
    for (; k + 16 <= end; k += 16) {
        unsigned p[16];
        #pragma unroll
        for (int q = 0; q < 16; ++q) p[q] = __builtin_nontemporal_load(pair + k + q);
        unsigned u[16];
        #pragma unroll
        for (int q = 0; q < 16; ++q) u[q] = e16[(size_t)(p[q] & 0x1FFFFu) * 64 + lane];
        #pragma unroll
        for (int q = 0; q < 16; ++q) {
            float w = w15dec(p[q] >> 17);
            ax += w * __uint_as_float(u[q] << 16);
            ay += w * __uint_as_float(u[q] & 0xffff0000u);
            ws += w;
        }
    }
    for (; k + 4 <= end; k += 4) {
        unsigned p[4];
        #pragma unroll
        for (int q = 0; q < 4; ++q) p[q] = __builtin_nontemporal_load(pair + k + q);
        unsigned u[4];
        #pragma unroll
        for (int q = 0; q < 4; ++q) u[q] = e16[(size_t)(p[q] & 0x1FFFFu) * 64 + lane];
        #pragma unroll
        for (int q = 0; q < 4; ++q) {
            float w = w15dec(p[q] >> 17);
            ax += w * __uint_as_float(u[q] << 16);
            ay += w * __uint_as_float(u[q] & 0xffff0000u);
            ws += w;
        }
    }
    for (; k < end; ++k) {
        unsigned p0 = __builtin_nontemporal_load(pair + k);
        float w0 = w15dec(p0 >> 17);
        unsigned ua = e16[(size_t)(p0 & 0x1FFFFu) * 64 + lane];
        ax += w0 * __uint_as_float(ua << 16);
        ay += w0 * __uint_as_float(ua & 0xffff0000u);
        ws += w0;
    }
    float inv = (ws > 0.f) ? 1.f / ws : 0.f;
    f32x2 o = {ax * inv, ay * inv};
    __builtin_nontemporal_store(o, (f32x2*)out + (size_t)wid * 64 + lane);
}

extern "C" void kernel_launch(void* const* d_in, const int* in_sizes, int n_in,
                              void* d_out, int out_size, void* d_ws, size_t ws_size,
                              hipStream_t stream)
{
    const float* nf   = (const float*)d_in[0];
    const float* data = (const float*)d_in[1];
    const float* W    = (const float*)d_in[2];
    const float* b    = (const float*)d_in[3];
    const int*   vi   = (const int*)d_in[4];
    const int*   ei   = (const int*)d_in[5];

    const int n   = in_sizes[0] / DF;   // 100000
    const int nnz = in_sizes[1];        // 1000000
    const int m   = ME;                 // 20000

    // epb: multiple of 1024 so each block's quad loop is exact & 16B-aligned
    const int epb = ((nnz + NB - 1) / NB + 1023) & ~1023;   // 8192 for 1M

    // -------- workspace layout (~70.4 MB; e16 aliases the dead ranks) ------
    int*   seg   = (int*)d_ws;                  // [m+n] starts (never mutated)
    int*   bsum  = seg + (m + n);               // [256]
    int*   totE  = bsum + 256;                  // [m]
    int*   totV  = totE + m;                    // [n]
    // alias region: ranks (4 MB, dead after place) / e16 (5.12 MB, born after)
    unsigned short* rankE = (unsigned short*)(totV + n);   // [nnz] u16
    unsigned short* rankV = rankE + nnz;                   // [nnz] u16
    unsigned* e16 = (unsigned*)rankE;                      // [m*64] (alias)
    unsigned* pair = (unsigned*)rankE + ((size_t)m * 64 > (size_t)nnz ?
                     (size_t)m * 64 : (size_t)nnz);        // after max(e16,ranks)
    unsigned* wp  = pair + 2 * (size_t)nnz;     // [DF*64]
    unsigned* nfh = wp + DF * 64;               // [n*64]
    unsigned* bhE = nfh + (size_t)n * 64;       // [NB*EW] packed counts->bases
    unsigned* bhV = bhE + (size_t)NB * EW;      // [NB*VP*VW] packed counts->bases
    float* out   = (float*)d_out;

    hist_lds<<<NB, 256, 0, stream>>>(vi, ei, rankE, rankV, bhE, bhV, nnz, epb);

    scan_cols_conv<<<512, 256, 0, stream>>>(bhE, bhV, totE, totV,
                                            nf, W, nfh, wp, n, n * 64);

    int len = m + n;
    int nb = (len + 2047) / 2048;
    scan_k1<<<nb, 256, 0, stream>>>(totE, totV, bsum, m, len);
    scan_k2<<<1, 256, 0, stream>>>(bsum, nb);
    scan_k3<<<nb, 256, 0, stream>>>(totE, totV, bsum, seg, m, len);

    int nbQ = (nnz / 4 + 255) / 256;
    place_kernel<<<nbQ, 256, 0, stream>>>(vi, ei, data, rankE, rankV, seg,
                                          bhE, bhV, pair, nnz, m, epb);

    gather_y_linear<<<(m + 3) / 4, 256, 0, stream>>>(nfh, seg, pair, wp, b, e16, m);
    gather_out<<<(n + 3) / 4, 256, 0, stream>>>(e16, seg, pair, out, n, m, 2 * nnz);
}

// Round 20
// 241.967 us; speedup vs baseline: 1.5605x; 1.0906x over previous
//
#include <hip/hip_runtime.h>

#define DF  128
#define NB  128    // hist blocks (chunked LDS hists)
#define ME  20000  // m (python scalar; fixed problem constant)
#define EW  10000  // e-hist packed words (2 keys/word)
#define VW  25000  // v-hist packed words per pass (covers 50000 keys, 100KB LDS)
#define VP  2      // v passes (2*50000 == 100000 == n)
#define VSPAN (2 * VW)

typedef float f32x2 __attribute__((ext_vector_type(2)));

__device__ __forceinline__ unsigned bf16rne(float f) {
    unsigned u = __float_as_uint(f);
    return (u + 0x7fffu + ((u >> 16) & 1u)) >> 16;
}

// weight <-> 15-bit float (e5 biased at 96, m10). data in [0,1) -> exact fit.
__device__ __forceinline__ unsigned w15enc(float f) {
    unsigned bits = __float_as_uint(f);
    unsigned r = (bits + 0xFFFu + ((bits >> 13) & 1u)) >> 13;   // RNE
    return (r > (96u << 10)) ? (r - (96u << 10)) : 0u;
}
__device__ __forceinline__ float w15dec(unsigned w) {
    return w ? __uint_as_float((w + (96u << 10)) << 13) : 0.f;
}

// packed-bf16 dot2: acc += a.lo*b.lo + a.hi*b.hi
#if __has_builtin(__builtin_amdgcn_fdot2_f32_bf16)
typedef __bf16 bf16x2 __attribute__((ext_vector_type(2)));
__device__ __forceinline__ float dot2bf(unsigned a, unsigned b, float c) {
    return __builtin_amdgcn_fdot2_f32_bf16(
        __builtin_bit_cast(bf16x2, a), __builtin_bit_cast(bf16x2, b), c, false);
}
#else
__device__ __forceinline__ float dot2bf(unsigned a, unsigned b, float c) {
    c += __uint_as_float(a << 16) * __uint_as_float(b << 16);
    c += __uint_as_float(a & 0xffff0000u) * __uint_as_float(b & 0xffff0000u);
    return c;
}
#endif

// ================= H1: all-LDS histograms + BOTH rank captures ==============
__global__ __launch_bounds__(256) void hist_lds(
    const int* __restrict__ vi, const int* __restrict__ ei,
    unsigned short* __restrict__ rankE, unsigned short* __restrict__ rankV,
    unsigned* __restrict__ bhE, unsigned* __restrict__ bhV, int nnz, int epb)
{
    __shared__ unsigned lh[VW];   // 100 KB; e-phase uses first EW words
    int b = blockIdx.x;
    int lo = b * epb;
    int hi = min(nnz, lo + epb);
    int iters = epb >> 10;        // epb multiple of 1024

    // ---- e phase ----
    for (int w = threadIdx.x; w < EW; w += 256) lh[w] = 0;
    __syncthreads();
    for (int it = 0; it < iters; ++it) {
        int i = lo + (it * 256 + threadIdx.x) * 4;
        if (i + 4 <= hi) {
            int4 e4 = *(const int4*)(ei + i);
            int ee[4] = {e4.x, e4.y, e4.z, e4.w};
            unsigned short r[4];
            #pragma unroll
            for (int q = 0; q < 4; ++q) {
                int sh = (ee[q] & 1) * 16;
                unsigned ret = atomicAdd(&lh[ee[q] >> 1], 1u << sh);
                r[q] = (unsigned short)((ret >> sh) & 0xffffu);
            }
            *(ushort4*)(rankE + i) = ushort4{r[0], r[1], r[2], r[3]};
        } else {
            for (int j = i; j < hi; ++j) {
                int e = ei[j]; int sh = (e & 1) * 16;
                unsigned ret = atomicAdd(&lh[e >> 1], 1u << sh);
                rankE[j] = (unsigned short)((ret >> sh) & 0xffffu);
            }
        }
    }
    __syncthreads();
    for (int w = threadIdx.x; w < EW; w += 256)
        bhE[(size_t)b * EW + w] = lh[w];

    // ---- v passes (counts + rank capture) ----
    for (int p = 0; p < VP; ++p) {
        int vbase = p * VSPAN;
        __syncthreads();
        for (int w = threadIdx.x; w < VW; w += 256) lh[w] = 0;
        __syncthreads();
        for (int it = 0; it < iters; ++it) {
            int i = lo + (it * 256 + threadIdx.x) * 4;
            if (i + 4 <= hi) {
                int4 v4 = *(const int4*)(vi + i);
                int vv[4] = {v4.x, v4.y, v4.z, v4.w};
                #pragma unroll
                for (int q = 0; q < 4; ++q) {
                    int d = vv[q] - vbase;
                    if (d >= 0 && d < VSPAN) {
                        int sh = (d & 1) * 16;
                        unsigned ret = atomicAdd(&lh[d >> 1], 1u << sh);
                        rankV[i + q] = (unsigned short)((ret >> sh) & 0xffffu);
                    }
                }
            } else {
                for (int j = i; j < hi; ++j) {
                    int d = vi[j] - vbase;
                    if (d >= 0 && d < VSPAN) {
                        int sh = (d & 1) * 16;
                        unsigned ret = atomicAdd(&lh[d >> 1], 1u << sh);
                        rankV[j] = (unsigned short)((ret >> sh) & 0xffffu);
                    }
                }
            }
        }
        __syncthreads();
        for (int w = threadIdx.x; w < VW; w += 256)
            bhV[(size_t)b * (VP * VW) + p * VW + w] = lh[w];
    }
}

// ===== S1: column scans (hist->bases, packed, BOTH sides) + conversions =====
__global__ __launch_bounds__(256) void scan_cols_conv(
    unsigned* __restrict__ bhE, unsigned* __restrict__ bhV,
    int* __restrict__ totE, int* __restrict__ totV,
    const float* __restrict__ nf, const float* __restrict__ W,
    unsigned* __restrict__ nfh, unsigned* __restrict__ wp, int n, int n64)
{
    int tid = blockIdx.x * 256 + threadIdx.x;
    if (tid < EW) {
        unsigned run0 = 0, run1 = 0;
        #pragma unroll 4
        for (int b = 0; b < NB; ++b) {
            unsigned w = bhE[(size_t)b * EW + tid];
            bhE[(size_t)b * EW + tid] = run0 | (run1 << 16);   // exclusive bases
            run0 += w & 0xffffu; run1 += w >> 16;
        }
        totE[2 * tid] = (int)run0;
        totE[2 * tid + 1] = (int)run1;
    } else if (tid < EW + VP * VW) {
        int w = tid - EW;                    // word in [0, VP*VW)
        unsigned run0 = 0, run1 = 0;
        #pragma unroll 4
        for (int b = 0; b < NB; ++b) {
            unsigned x = bhV[(size_t)b * (VP * VW) + w];
            bhV[(size_t)b * (VP * VW) + w] = run0 | (run1 << 16);  // bases
            run0 += x & 0xffffu; run1 += x >> 16;
        }
        int p = w / VW, wi = w - p * VW;
        int k0 = p * VSPAN + 2 * wi;
        if (k0 < n) totV[k0] = (int)run0;
        if (k0 + 1 < n) totV[k0 + 1] = (int)run1;
    }
    // ---- conversions (grid-stride) ----
    int nth = gridDim.x * 256;
    const float2* __restrict__ in2 = (const float2*)nf;
    for (int i = tid; i < n64; i += nth) {
        float2 f = in2[i];
        nfh[i] = bf16rne(f.x) | (bf16rne(f.y) << 16);
    }
    if (tid < DF * 64) {
        int j = tid >> 6, k2 = tid & 63;
        float2 f = ((const float2*)W)[tid];
        wp[k2 * DF + j] = bf16rne(f.x) | (bf16rne(f.y) << 16);
    }
}

// ================= scans: exclusive prefix over [totE | totV] ===============
__global__ __launch_bounds__(256) void scan_k1(
    const int* __restrict__ totE, const int* __restrict__ totV,
    int* __restrict__ bsum, int m, int len)
{
    __shared__ int s[256];
    int tid = threadIdx.x;
    int base = blockIdx.x * 2048 + tid * 8;
    int t = 0;
    #pragma unroll
    for (int i = 0; i < 8; ++i) {
        int idx = base + i;
        if (idx < len) t += (idx < m) ? totE[idx] : totV[idx - m];
    }
    s[tid] = t; __syncthreads();
    for (int d = 128; d > 0; d >>= 1) {
        if (tid < d) s[tid] += s[tid + d];
        __syncthreads();
    }
    if (tid == 0) bsum[blockIdx.x] = s[0];
}

__global__ __launch_bounds__(256) void scan_k2(int* __restrict__ bsum, int nb)
{
    __shared__ int s[256];
    int t = threadIdx.x;
    int v = (t < nb) ? bsum[t] : 0;
    s[t] = v; __syncthreads();
    for (int d = 1; d < 256; d <<= 1) {
        int u = (t >= d) ? s[t - d] : 0;
        __syncthreads();
        s[t] += u;
        __syncthreads();
    }
    if (t < nb) bsum[t] = s[t] - v;   // exclusive
}

__global__ __launch_bounds__(256) void scan_k3(
    const int* __restrict__ totE, const int* __restrict__ totV,
    const int* __restrict__ bsum, int* __restrict__ seg, int m, int len)
{
    __shared__ int s[256];
    int tid = threadIdx.x;
    int base = blockIdx.x * 2048 + tid * 8;
    int v[8]; int t = 0;
    #pragma unroll
    for (int i = 0; i < 8; ++i) {
        int idx = base + i;
        v[i] = (idx < len) ? ((idx < m) ? totE[idx] : totV[idx - m]) : 0;
        t += v[i];
    }
    s[tid] = t; __syncthreads();
    for (int d = 1; d < 256; d <<= 1) {
        int u = (tid >= d) ? s[tid - d] : 0;
        __syncthreads();
        s[tid] += u;
        __syncthreads();
    }
    int run = bsum[blockIdx.x] + (s[tid] - t);
    #pragma unroll
    for (int i = 0; i < 8; ++i) {
        int idx = base + i;
        if (idx < len) { seg[idx] = run; run += v[i]; }
    }
}

// ============ placement: FULLY atomic-free scatter (both sides) =============
// Pair stores are REGULAR (not NT): pair is 8 MB, lines accumulate ~16
// entries each — evict-first NT hint caused premature partial writebacks
// (r19: WRITE 65 MB for an 8 MB buffer).
__global__ __launch_bounds__(256) void place_kernel(
    const int* __restrict__ vi, const int* __restrict__ ei,
    const float* __restrict__ data,
    const unsigned short* __restrict__ rankE,
    const unsigned short* __restrict__ rankV,
    const int* __restrict__ seg,
    const unsigned* __restrict__ bhE, const unsigned* __restrict__ bhV,
    unsigned* __restrict__ pair, int nnz, int m, int epb)
{
    int base = (blockIdx.x * 256 + threadIdx.x) * 4;
    if (base + 4 <= nnz) {
        int bH = base / epb;               // quad never straddles (epb %4==0)
        const unsigned* __restrict__ be = bhE + (size_t)bH * EW;
        const unsigned* __restrict__ bv = bhV + (size_t)bH * (VP * VW);
        int4 e4 = *(const int4*)(ei + base);
        int4 v4 = *(const int4*)(vi + base);
        ushort4 re4 = *(const ushort4*)(rankE + base);
        ushort4 rv4 = *(const ushort4*)(rankV + base);
        float4 d4 = *(const float4*)(data + base);
        int ee[4] = {e4.x, e4.y, e4.z, e4.w};
        int vv[4] = {v4.x, v4.y, v4.z, v4.w};
        unsigned short rre[4] = {re4.x, re4.y, re4.z, re4.w};
        unsigned short rrv[4] = {rv4.x, rv4.y, rv4.z, rv4.w};
        float dd[4] = {d4.x, d4.y, d4.z, d4.w};
        #pragma unroll
        for (int q = 0; q < 4; ++q) {
            unsigned w15 = w15enc(dd[q]) << 17;
            unsigned bwE = be[ee[q] >> 1];
            int baseE = (int)((bwE >> ((ee[q] & 1) * 16)) & 0xffffu);
            int p = vv[q] / VSPAN;
            int d = vv[q] - p * VSPAN;
            unsigned bwV = bv[p * VW + (d >> 1)];
            int baseV = (int)((bwV >> ((d & 1) * 16)) & 0xffffu);
            int pe = seg[ee[q]] + baseE + rre[q];
            int pv = seg[m + vv[q]] + baseV + rrv[q];
            pair[pe] = w15 | (unsigned)vv[q];
            pair[pv] = w15 | (unsigned)ee[q];
        }
    } else {
        for (int i = base; i < nnz; ++i) {
            int bH = i / epb;
            int e = ei[i], v = vi[i];
            unsigned w15 = w15enc(data[i]) << 17;
            unsigned bwE = bhE[(size_t)bH * EW + (e >> 1)];
            int baseE = (int)((bwE >> ((e & 1) * 16)) & 0xffffu);
            int p = v / VSPAN;
            int d = v - p * VSPAN;
            unsigned bwV = bhV[(size_t)bH * (VP * VW) + p * VW + (d >> 1)];
            int baseV = (int)((bwV >> ((d & 1) * 16)) & 0xffffu);
            int pe = seg[e] + baseE + rankE[i];
            int pv = seg[m + v] + baseV + rankV[i];
            pair[pe] = w15 | (unsigned)v;
            pair[pv] = w15 | (unsigned)e;
        }
    }
}

// ======== fused gather_y + linear: e16[s] = bf16( (d_e>0) ? yrow@W^T+b : 0 ) =
__global__ __launch_bounds__(256) void gather_y_linear(
    const unsigned* __restrict__ nfh, const int* __restrict__ seg,
    const unsigned* __restrict__ pair, const unsigned* __restrict__ wp,
    const float* __restrict__ b, unsigned* __restrict__ e16, int m)
{
    __shared__ unsigned rowbuf[4][64];
    int wv = threadIdx.x >> 6;
    int wid = (blockIdx.x * 256 + threadIdx.x) >> 6;
    int lane = threadIdx.x & 63;
    if (wid >= m) return;
    int start = seg[wid];
    int end   = seg[wid + 1];      // seg[m] == nnz (start of v-CSR); never mutated
    float ax = 0.f, ay = 0.f, ws = 0.f;
    int k = start;
    for (; k + 16 <= end; k += 16) {
        unsigned p[16];
        #pragma unroll
        for (int q = 0; q < 16; ++q) p[q] = __builtin_nontemporal_load(pair + k + q);
        unsigned u[16];
        #pragma unroll
        for (int q = 0; q < 16; ++q) u[q] = nfh[(size_t)(p[q] & 0x1FFFFu) * 64 + lane];
        #pragma unroll
        for (int q = 0; q < 16; ++q) {
            float w = w15dec(p[q] >> 17);
            ax += w * __uint_as_float(u[q] << 16);
            ay += w * __uint_as_float(u[q] & 0xffff0000u);
            ws += w;
        }
    }
    for (; k + 4 <= end; k += 4) {
        unsigned p[4];
        #pragma unroll
        for (int q = 0; q < 4; ++q) p[q] = __builtin_nontemporal_load(pair + k + q);
        unsigned u[4];
        #pragma unroll
        for (int q = 0; q < 4; ++q) u[q] = nfh[(size_t)(p[q] & 0x1FFFFu) * 64 + lane];
        #pragma unroll
        for (int q = 0; q < 4; ++q) {
            float w = w15dec(p[q] >> 17);
            ax += w * __uint_as_float(u[q] << 16);
            ay += w * __uint_as_float(u[q] & 0xffff0000u);
            ws += w;
        }
    }
    for (; k < end; ++k) {
        unsigned p0 = __builtin_nontemporal_load(pair + k);
        float w0 = w15dec(p0 >> 17);
        unsigned ua = nfh[(size_t)(p0 & 0x1FFFFu) * 64 + lane];
        ax += w0 * __uint_as_float(ua << 16);
        ay += w0 * __uint_as_float(ua & 0xffff0000u);
        ws += w0;
    }
    float inv = (ws > 0.f) ? 1.f / ws : 0.f;
    rowbuf[wv][lane] = bf16rne(ax * inv) | (bf16rne(ay * inv) << 16);
    // wave-private LDS region: in-wave ds ordering suffices, no barrier.

    float2 bb = ((const float2*)b)[lane];
    float acc0 = (ws > 0.f) ? bb.x : 0.f;
    float acc1 = (ws > 0.f) ? bb.y : 0.f;
    const unsigned* __restrict__ row = rowbuf[wv];
    #pragma unroll 8
    for (int k2 = 0; k2 < 64; ++k2) {
        unsigned r = row[k2];                         // broadcast (y[2k2],y[2k2+1])
        uint2 u = ((const uint2*)(wp + k2 * DF))[lane];
        acc0 = dot2bf(r, u.x, acc0);
        acc1 = dot2bf(r, u.y, acc1);
    }
    e16[(size_t)wid * 64 + lane] = bf16rne(acc0) | (bf16rne(acc1) << 16);
}

// ================= gather_out: out[v] = segsum(w*e16[eidx]) / d_v ===========
__global__ __launch_bounds__(256) void gather_out(
    const unsigned* __restrict__ e16, const int* __restrict__ seg,
    const unsigned* __restrict__ pair,
    float* __restrict__ out, int n, int m, int tot)
{
    int wid = (blockIdx.x * 256 + threadIdx.x) >> 6;
    int lane = threadIdx.x & 63;
    if (wid >= n) return;
    int idx = m + wid;
    int start = seg[idx];
    int end   = (wid == n - 1) ? tot : seg[idx + 1];
    float ax = 0.f, ay = 0.f, ws = 0.f;
    int k = start;
    for (; k + 16 <= end; k += 16) {
        unsigned p[16];
        #pragma unroll
        for (int q = 0; q < 16; ++q) p[q] = __builtin_nontemporal_load(pair + k + q);
        unsigned u[16];
        #pragma unroll
        for (int q = 0; q < 16; ++q) u[q] = e16[(size_t)(p[q] & 0x1FFFFu) * 64 + lane];
        #pragma unroll
        for (int q = 0; q < 16; ++q) {
            float w = w15dec(p[q] >> 17);
            ax += w * __uint_as_float(u[q] << 16);
            ay += w * __uint_as_float(u[q] & 0xffff0000u);
            ws += w;
        }
    }
    for (; k + 4 <= end; k += 4) {
        unsigned p[4];
        #pragma unroll
        for (int q = 0; q < 4; ++q) p[q] = __builtin_nontemporal_load(pair + k + q);
        unsigned u[4];
        #pragma unroll
        for (int q = 0; q < 4; ++q) u[q] = e16[(size_t)(p[q] & 0x1FFFFu) * 64 + lane];
        #pragma unroll
        for (int q = 0; q < 4; ++q) {
            float w = w15dec(p[q] >> 17);
            ax += w * __uint_as_float(u[q] << 16);
            ay += w * __uint_as_float(u[q] & 0xffff0000u);
            ws += w;
        }
    }
    for (; k < end; ++k) {
        unsigned p0 = __builtin_nontemporal_load(pair + k);
        float w0 = w15dec(p0 >> 17);
        unsigned ua = e16[(size_t)(p0 & 0x1FFFFu) * 64 + lane];
        ax += w0 * __uint_as_float(ua << 16);
        ay += w0 * __uint_as_float(ua & 0xffff0000u);
        ws += w0;
    }
    float inv = (ws > 0.f) ? 1.f / ws : 0.f;
    f32x2 o = {ax * inv, ay * inv};
    __builtin_nontemporal_store(o, (f32x2*)out + (size_t)wid * 64 + lane);
}

extern "C" void kernel_launch(void* const* d_in, const int* in_sizes, int n_in,
                              void* d_out, int out_size, void* d_ws, size_t ws_size,
                              hipStream_t stream)
{
    const float* nf   = (const float*)d_in[0];
    const float* data = (const float*)d_in[1];
    const float* W    = (const float*)d_in[2];
    const float* b    = (const float*)d_in[3];
    const int*   vi   = (const int*)d_in[4];
    const int*   ei   = (const int*)d_in[5];

    const int n   = in_sizes[0] / DF;   // 100000
    const int nnz = in_sizes[1];        // 1000000
    const int m   = ME;                 // 20000

    // epb: multiple of 1024 so each block's quad loop is exact & 16B-aligned
    const int epb = ((nnz + NB - 1) / NB + 1023) & ~1023;   // 8192 for 1M

    // -------- workspace layout (~70.4 MB; e16 aliases the dead ranks) ------
    int*   seg   = (int*)d_ws;                  // [m+n] starts (never mutated)
    int*   bsum  = seg + (m + n);               // [256]
    int*   totE  = bsum + 256;                  // [m]
    int*   totV  = totE + m;                    // [n]
    // alias region: ranks (4 MB, dead after place) / e16 (5.12 MB, born after)
    unsigned short* rankE = (unsigned short*)(totV + n);   // [nnz] u16
    unsigned short* rankV = rankE + nnz;                   // [nnz] u16
    unsigned* e16 = (unsigned*)rankE;                      // [m*64] (alias)
    unsigned* pair = (unsigned*)rankE + ((size_t)m * 64 > (size_t)nnz ?
                     (size_t)m * 64 : (size_t)nnz);        // after max(e16,ranks)
    unsigned* wp  = pair + 2 * (size_t)nnz;     // [DF*64]
    unsigned* nfh = wp + DF * 64;               // [n*64]
    unsigned* bhE = nfh + (size_t)n * 64;       // [NB*EW] packed counts->bases
    unsigned* bhV = bhE + (size_t)NB * EW;      // [NB*VP*VW] packed counts->bases
    float* out   = (float*)d_out;

    hist_lds<<<NB, 256, 0, stream>>>(vi, ei, rankE, rankV, bhE, bhV, nnz, epb);

    scan_cols_conv<<<512, 256, 0, stream>>>(bhE, bhV, totE, totV,
                                            nf, W, nfh, wp, n, n * 64);

    int len = m + n;
    int nb = (len + 2047) / 2048;
    scan_k1<<<nb, 256, 0, stream>>>(totE, totV, bsum, m, len);
    scan_k2<<<1, 256, 0, stream>>>(bsum, nb);
    scan_k3<<<nb, 256, 0, stream>>>(totE, totV, bsum, seg, m, len);

    int nbQ = (nnz / 4 + 255) / 256;
    place_kernel<<<nbQ, 256, 0, stream>>>(vi, ei, data, rankE, rankV, seg,
                                          bhE, bhV, pair, nnz, m, epb);

    gather_y_linear<<<(m + 3) / 4, 256, 0, stream>>>(nfh, seg, pair, wp, b, e16, m);
    gather_out<<<(n + 3) / 4, 256, 0, stream>>>(e16, seg, pair, out, n, m, 2 * nnz);
}

// Round 21
// 230.257 us; speedup vs baseline: 1.6399x; 1.0509x over previous
//
#include <hip/hip_runtime.h>

#define DF  128
#define NB  128    // hist blocks (chunked LDS hists)
#define ME  20000  // m (python scalar; fixed problem constant)
#define EW  10000  // e-hist packed words (2 keys/word)
#define VW  25000  // v-hist packed words per pass (covers 50000 keys, 100KB LDS)
#define VP  2      // v passes (2*50000 == 100000 == n)
#define VSPAN (2 * VW)

typedef float f32x2 __attribute__((ext_vector_type(2)));

__device__ __forceinline__ unsigned bf16rne(float f) {
    unsigned u = __float_as_uint(f);
    return (u + 0x7fffu + ((u >> 16) & 1u)) >> 16;
}

// weight <-> 15-bit float (e5 biased at 96, m10). data in [0,1) -> exact fit.
__device__ __forceinline__ unsigned w15enc(float f) {
    unsigned bits = __float_as_uint(f);
    unsigned r = (bits + 0xFFFu + ((bits >> 13) & 1u)) >> 13;   // RNE
    return (r > (96u << 10)) ? (r - (96u << 10)) : 0u;
}
__device__ __forceinline__ float w15dec(unsigned w) {
    return w ? __uint_as_float((w + (96u << 10)) << 13) : 0.f;
}

// packed-bf16 dot2: acc += a.lo*b.lo + a.hi*b.hi
#if __has_builtin(__builtin_amdgcn_fdot2_f32_bf16)
typedef __bf16 bf16x2 __attribute__((ext_vector_type(2)));
__device__ __forceinline__ float dot2bf(unsigned a, unsigned b, float c) {
    return __builtin_amdgcn_fdot2_f32_bf16(
        __builtin_bit_cast(bf16x2, a), __builtin_bit_cast(bf16x2, b), c, false);
}
#else
__device__ __forceinline__ float dot2bf(unsigned a, unsigned b, float c) {
    c += __uint_as_float(a << 16) * __uint_as_float(b << 16);
    c += __uint_as_float(a & 0xffff0000u) * __uint_as_float(b & 0xffff0000u);
    return c;
}
#endif

// ================= H1: all-LDS histograms + BOTH rank captures ==============
__global__ __launch_bounds__(256) void hist_lds(
    const int* __restrict__ vi, const int* __restrict__ ei,
    unsigned short* __restrict__ rankE, unsigned short* __restrict__ rankV,
    unsigned* __restrict__ bhE, unsigned* __restrict__ bhV, int nnz, int epb)
{
    __shared__ unsigned lh[VW];   // 100 KB; e-phase uses first EW words
    int b = blockIdx.x;
    int lo = b * epb;
    int hi = min(nnz, lo + epb);
    int iters = epb >> 10;        // epb multiple of 1024

    // ---- e phase ----
    for (int w = threadIdx.x; w < EW; w += 256) lh[w] = 0;
    __syncthreads();
    for (int it = 0; it < iters; ++it) {
        int i = lo + (it * 256 + threadIdx.x) * 4;
        if (i + 4 <= hi) {
            int4 e4 = *(const int4*)(ei + i);
            int ee[4] = {e4.x, e4.y, e4.z, e4.w};
            unsigned short r[4];
            #pragma unroll
            for (int q = 0; q < 4; ++q) {
                int sh = (ee[q] & 1) * 16;
                unsigned ret = atomicAdd(&lh[ee[q] >> 1], 1u << sh);
                r[q] = (unsigned short)((ret >> sh) & 0xffffu);
            }
            *(ushort4*)(rankE + i) = ushort4{r[0], r[1], r[2], r[3]};
        } else {
            for (int j = i; j < hi; ++j) {
                int e = ei[j]; int sh = (e & 1) * 16;
                unsigned ret = atomicAdd(&lh[e >> 1], 1u << sh);
                rankE[j] = (unsigned short)((ret >> sh) & 0xffffu);
            }
        }
    }
    __syncthreads();
    for (int w = threadIdx.x; w < EW; w += 256)
        bhE[(size_t)b * EW + w] = lh[w];

    // ---- v passes (counts + rank capture) ----
    for (int p = 0; p < VP; ++p) {
        int vbase = p * VSPAN;
        __syncthreads();
        for (int w = threadIdx.x; w < VW; w += 256) lh[w] = 0;
        __syncthreads();
        for (int it = 0; it < iters; ++it) {
            int i = lo + (it * 256 + threadIdx.x) * 4;
            if (i + 4 <= hi) {
                int4 v4 = *(const int4*)(vi + i);
                int vv[4] = {v4.x, v4.y, v4.z, v4.w};
                #pragma unroll
                for (int q = 0; q < 4; ++q) {
                    int d = vv[q] - vbase;
                    if (d >= 0 && d < VSPAN) {
                        int sh = (d & 1) * 16;
                        unsigned ret = atomicAdd(&lh[d >> 1], 1u << sh);
                        rankV[i + q] = (unsigned short)((ret >> sh) & 0xffffu);
                    }
                }
            } else {
                for (int j = i; j < hi; ++j) {
                    int d = vi[j] - vbase;
                    if (d >= 0 && d < VSPAN) {
                        int sh = (d & 1) * 16;
                        unsigned ret = atomicAdd(&lh[d >> 1], 1u << sh);
                        rankV[j] = (unsigned short)((ret >> sh) & 0xffffu);
                    }
                }
            }
        }
        __syncthreads();
        for (int w = threadIdx.x; w < VW; w += 256)
            bhV[(size_t)b * (VP * VW) + p * VW + w] = lh[w];
    }
}

// ===== S1: column scans (hist->bases, packed, BOTH sides) + conversions =====
__global__ __launch_bounds__(256) void scan_cols_conv(
    unsigned* __restrict__ bhE, unsigned* __restrict__ bhV,
    int* __restrict__ totE, int* __restrict__ totV,
    const float* __restrict__ nf, const float* __restrict__ W,
    unsigned* __restrict__ nfh, unsigned* __restrict__ wp, int n, int n64)
{
    int tid = blockIdx.x * 256 + threadIdx.x;
    if (tid < EW) {
        unsigned run0 = 0, run1 = 0;
        #pragma unroll 4
        for (int b = 0; b < NB; ++b) {
            unsigned w = bhE[(size_t)b * EW + tid];
            bhE[(size_t)b * EW + tid] = run0 | (run1 << 16);   // exclusive bases
            run0 += w & 0xffffu; run1 += w >> 16;
        }
        totE[2 * tid] = (int)run0;
        totE[2 * tid + 1] = (int)run1;
    } else if (tid < EW + VP * VW) {
        int w = tid - EW;                    // word in [0, VP*VW)
        unsigned run0 = 0, run1 = 0;
        #pragma unroll 4
        for (int b = 0; b < NB; ++b) {
            unsigned x = bhV[(size_t)b * (VP * VW) + w];
            bhV[(size_t)b * (VP * VW) + w] = run0 | (run1 << 16);  // bases
            run0 += x & 0xffffu; run1 += x >> 16;
        }
        int p = w / VW, wi = w - p * VW;
        int k0 = p * VSPAN + 2 * wi;
        if (k0 < n) totV[k0] = (int)run0;
        if (k0 + 1 < n) totV[k0 + 1] = (int)run1;
    }
    // ---- conversions (grid-stride) ----
    int nth = gridDim.x * 256;
    const float2* __restrict__ in2 = (const float2*)nf;
    for (int i = tid; i < n64; i += nth) {
        float2 f = in2[i];
        nfh[i] = bf16rne(f.x) | (bf16rne(f.y) << 16);
    }
    if (tid < DF * 64) {
        int j = tid >> 6, k2 = tid & 63;
        float2 f = ((const float2*)W)[tid];
        wp[k2 * DF + j] = bf16rne(f.x) | (bf16rne(f.y) << 16);
    }
}

// ================= scans: exclusive prefix over [totE | totV] ===============
__global__ __launch_bounds__(256) void scan_k1(
    const int* __restrict__ totE, const int* __restrict__ totV,
    int* __restrict__ bsum, int m, int len)
{
    __shared__ int s[256];
    int tid = threadIdx.x;
    int base = blockIdx.x * 2048 + tid * 8;
    int t = 0;
    #pragma unroll
    for (int i = 0; i < 8; ++i) {
        int idx = base + i;
        if (idx < len) t += (idx < m) ? totE[idx] : totV[idx - m];
    }
    s[tid] = t; __syncthreads();
    for (int d = 128; d > 0; d >>= 1) {
        if (tid < d) s[tid] += s[tid + d];
        __syncthreads();
    }
    if (tid == 0) bsum[blockIdx.x] = s[0];
}

__global__ __launch_bounds__(256) void scan_k2(int* __restrict__ bsum, int nb)
{
    __shared__ int s[256];
    int t = threadIdx.x;
    int v = (t < nb) ? bsum[t] : 0;
    s[t] = v; __syncthreads();
    for (int d = 1; d < 256; d <<= 1) {
        int u = (t >= d) ? s[t - d] : 0;
        __syncthreads();
        s[t] += u;
        __syncthreads();
    }
    if (t < nb) bsum[t] = s[t] - v;   // exclusive
}

__global__ __launch_bounds__(256) void scan_k3(
    const int* __restrict__ totE, const int* __restrict__ totV,
    const int* __restrict__ bsum, int* __restrict__ seg, int m, int len)
{
    __shared__ int s[256];
    int tid = threadIdx.x;
    int base = blockIdx.x * 2048 + tid * 8;
    int v[8]; int t = 0;
    #pragma unroll
    for (int i = 0; i < 8; ++i) {
        int idx = base + i;
        v[i] = (idx < len) ? ((idx < m) ? totE[idx] : totV[idx - m]) : 0;
        t += v[i];
    }
    s[tid] = t; __syncthreads();
    for (int d = 1; d < 256; d <<= 1) {
        int u = (tid >= d) ? s[tid - d] : 0;
        __syncthreads();
        s[tid] += u;
        __syncthreads();
    }
    int run = bsum[blockIdx.x] + (s[tid] - t);
    #pragma unroll
    for (int i = 0; i < 8; ++i) {
        int idx = base + i;
        if (idx < len) { seg[idx] = run; run += v[i]; }
    }
}

// ============ placement: FULLY atomic-free scatter (both sides) =============
// Regular stores (not NT): pair lines accumulate ~16 entries in L2.
__global__ __launch_bounds__(256) void place_kernel(
    const int* __restrict__ vi, const int* __restrict__ ei,
    const float* __restrict__ data,
    const unsigned short* __restrict__ rankE,
    const unsigned short* __restrict__ rankV,
    const int* __restrict__ seg,
    const unsigned* __restrict__ bhE, const unsigned* __restrict__ bhV,
    unsigned* __restrict__ pair, int nnz, int m, int epb)
{
    int base = (blockIdx.x * 256 + threadIdx.x) * 4;
    if (base + 4 <= nnz) {
        int bH = base / epb;               // quad never straddles (epb %4==0)
        const unsigned* __restrict__ be = bhE + (size_t)bH * EW;
        const unsigned* __restrict__ bv = bhV + (size_t)bH * (VP * VW);
        int4 e4 = *(const int4*)(ei + base);
        int4 v4 = *(const int4*)(vi + base);
        ushort4 re4 = *(const ushort4*)(rankE + base);
        ushort4 rv4 = *(const ushort4*)(rankV + base);
        float4 d4 = *(const float4*)(data + base);
        int ee[4] = {e4.x, e4.y, e4.z, e4.w};
        int vv[4] = {v4.x, v4.y, v4.z, v4.w};
        unsigned short rre[4] = {re4.x, re4.y, re4.z, re4.w};
        unsigned short rrv[4] = {rv4.x, rv4.y, rv4.z, rv4.w};
        float dd[4] = {d4.x, d4.y, d4.z, d4.w};
        #pragma unroll
        for (int q = 0; q < 4; ++q) {
            unsigned w15 = w15enc(dd[q]) << 17;
            unsigned bwE = be[ee[q] >> 1];
            int baseE = (int)((bwE >> ((ee[q] & 1) * 16)) & 0xffffu);
            int p = vv[q] / VSPAN;
            int d = vv[q] - p * VSPAN;
            unsigned bwV = bv[p * VW + (d >> 1)];
            int baseV = (int)((bwV >> ((d & 1) * 16)) & 0xffffu);
            int pe = seg[ee[q]] + baseE + rre[q];
            int pv = seg[m + vv[q]] + baseV + rrv[q];
            pair[pe] = w15 | (unsigned)vv[q];
            pair[pv] = w15 | (unsigned)ee[q];
        }
    } else {
        for (int i = base; i < nnz; ++i) {
            int bH = i / epb;
            int e = ei[i], v = vi[i];
            unsigned w15 = w15enc(data[i]) << 17;
            unsigned bwE = bhE[(size_t)bH * EW + (e >> 1)];
            int baseE = (int)((bwE >> ((e & 1) * 16)) & 0xffffu);
            int p = v / VSPAN;
            int d = v - p * VSPAN;
            unsigned bwV = bhV[(size_t)bH * (VP * VW) + p * VW + (d >> 1)];
            int baseV = (int)((bwV >> ((d & 1) * 16)) & 0xffffu);
            int pe = seg[e] + baseE + rankE[i];
            int pv = seg[m + v] + baseV + rankV[i];
            pair[pe] = w15 | (unsigned)v;
            pair[pv] = w15 | (unsigned)e;
        }
    }
}

// ======== fused gather_y + linear: e16[s] = bf16( (d_e>0) ? yrow@W^T+b : 0 ) =
// Single predicated-16 gather loop: all 16 pair loads issue unconditionally
// (reading <=60B past `end` stays inside ws; masked entries -> p=0 -> w=0,
// row-0 gather is an L1 hit). Avg-50 segment: 4 rounds, tail in-flight.
__global__ __launch_bounds__(256) void gather_y_linear(
    const unsigned* __restrict__ nfh, const int* __restrict__ seg,
    const unsigned* __restrict__ pair, const unsigned* __restrict__ wp,
    const float* __restrict__ b, unsigned* __restrict__ e16, int m)
{
    __shared__ unsigned rowbuf[4][64];
    int wv = threadIdx.x >> 6;
    int wid = (blockIdx.x * 256 + threadIdx.x) >> 6;
    int lane = threadIdx.x & 63;
    if (wid >= m) return;
    int start = seg[wid];
    int end   = seg[wid + 1];      // seg[m] == nnz (start of v-CSR); never mutated
    float ax = 0.f, ay = 0.f, ws = 0.f;
    for (int k = start; k < end; k += 16) {
        unsigned p[16];
        #pragma unroll
        for (int q = 0; q < 16; ++q) {
            unsigned t = __builtin_nontemporal_load(pair + k + q);
            p[q] = (k + q < end) ? t : 0u;
        }
        unsigned u[16];
        #pragma unroll
        for (int q = 0; q < 16; ++q) u[q] = nfh[(size_t)(p[q] & 0x1FFFFu) * 64 + lane];
        #pragma unroll
        for (int q = 0; q < 16; ++q) {
            float w = w15dec(p[q] >> 17);
            ax += w * __uint_as_float(u[q] << 16);
            ay += w * __uint_as_float(u[q] & 0xffff0000u);
            ws += w;
        }
    }
    float inv = (ws > 0.f) ? 1.f / ws : 0.f;
    rowbuf[wv][lane] = bf16rne(ax * inv) | (bf16rne(ay * inv) << 16);
    // wave-private LDS region: in-wave ds ordering suffices, no barrier.

    float2 bb = ((const float2*)b)[lane];
    float acc0 = (ws > 0.f) ? bb.x : 0.f;
    float acc1 = (ws > 0.f) ? bb.y : 0.f;
    const unsigned* __restrict__ row = rowbuf[wv];
    #pragma unroll 8
    for (int k2 = 0; k2 < 64; ++k2) {
        unsigned r = row[k2];                         // broadcast (y[2k2],y[2k2+1])
        uint2 u = ((const uint2*)(wp + k2 * DF))[lane];
        acc0 = dot2bf(r, u.x, acc0);
        acc1 = dot2bf(r, u.y, acc1);
    }
    e16[(size_t)wid * 64 + lane] = bf16rne(acc0) | (bf16rne(acc1) << 16);
}

// ================= gather_out: out[v] = segsum(w*e16[eidx]) / d_v ===========
// Avg v-segment = 10 entries: the predicated-16 block turns 3-4 dependent
// latency rounds into ONE round of ~10 concurrent gathers.
__global__ __launch_bounds__(256) void gather_out(
    const unsigned* __restrict__ e16, const int* __restrict__ seg,
    const unsigned* __restrict__ pair,
    float* __restrict__ out, int n, int m, int tot)
{
    int wid = (blockIdx.x * 256 + threadIdx.x) >> 6;
    int lane = threadIdx.x & 63;
    if (wid >= n) return;
    int idx = m + wid;
    int start = seg[idx];
    int end   = (wid == n - 1) ? tot : seg[idx + 1];
    float ax = 0.f, ay = 0.f, ws = 0.f;
    for (int k = start; k < end; k += 16) {
        unsigned p[16];
        #pragma unroll
        for (int q = 0; q < 16; ++q) {
            unsigned t = __builtin_nontemporal_load(pair + k + q);
            p[q] = (k + q < end) ? t : 0u;
        }
        unsigned u[16];
        #pragma unroll
        for (int q = 0; q < 16; ++q) u[q] = e16[(size_t)(p[q] & 0x1FFFFu) * 64 + lane];
        #pragma unroll
        for (int q = 0; q < 16; ++q) {
            float w = w15dec(p[q] >> 17);
            ax += w * __uint_as_float(u[q] << 16);
            ay += w * __uint_as_float(u[q] & 0xffff0000u);
            ws += w;
        }
    }
    float inv = (ws > 0.f) ? 1.f / ws : 0.f;
    f32x2 o = {ax * inv, ay * inv};
    __builtin_nontemporal_store(o, (f32x2*)out + (size_t)wid * 64 + lane);
}

extern "C" void kernel_launch(void* const* d_in, const int* in_sizes, int n_in,
                              void* d_out, int out_size, void* d_ws, size_t ws_size,
                              hipStream_t stream)
{
    const float* nf   = (const float*)d_in[0];
    const float* data = (const float*)d_in[1];
    const float* W    = (const float*)d_in[2];
    const float* b    = (const float*)d_in[3];
    const int*   vi   = (const int*)d_in[4];
    const int*   ei   = (const int*)d_in[5];

    const int n   = in_sizes[0] / DF;   // 100000
    const int nnz = in_sizes[1];        // 1000000
    const int m   = ME;                 // 20000

    // epb: multiple of 1024 so each block's quad loop is exact & 16B-aligned
    const int epb = ((nnz + NB - 1) / NB + 1023) & ~1023;   // 8192 for 1M

    // -------- workspace layout (~70.4 MB; e16 aliases the dead ranks) ------
    int*   seg   = (int*)d_ws;                  // [m+n] starts (never mutated)
    int*   bsum  = seg + (m + n);               // [256]
    int*   totE  = bsum + 256;                  // [m]
    int*   totV  = totE + m;                    // [n]
    // alias region: ranks (4 MB, dead after place) / e16 (5.12 MB, born after)
    unsigned short* rankE = (unsigned short*)(totV + n);   // [nnz] u16
    unsigned short* rankV = rankE + nnz;                   // [nnz] u16
    unsigned* e16 = (unsigned*)rankE;                      // [m*64] (alias)
    unsigned* pair = (unsigned*)rankE + ((size_t)m * 64 > (size_t)nnz ?
                     (size_t)m * 64 : (size_t)nnz);        // after max(e16,ranks)
    unsigned* wp  = pair + 2 * (size_t)nnz;     // [DF*64]
    unsigned* nfh = wp + DF * 64;               // [n*64]
    unsigned* bhE = nfh + (size_t)n * 64;       // [NB*EW] packed counts->bases
    unsigned* bhV = bhE + (size_t)NB * EW;      // [NB*VP*VW] packed counts->bases
    float* out   = (float*)d_out;

    hist_lds<<<NB, 256, 0, stream>>>(vi, ei, rankE, rankV, bhE, bhV, nnz, epb);

    scan_cols_conv<<<512, 256, 0, stream>>>(bhE, bhV, totE, totV,
                                            nf, W, nfh, wp, n, n * 64);

    int len = m + n;
    int nb = (len + 2047) / 2048;
    scan_k1<<<nb, 256, 0, stream>>>(totE, totV, bsum, m, len);
    scan_k2<<<1, 256, 0, stream>>>(bsum, nb);
    scan_k3<<<nb, 256, 0, stream>>>(totE, totV, bsum, seg, m, len);

    int nbQ = (nnz / 4 + 255) / 256;
    place_kernel<<<nbQ, 256, 0, stream>>>(vi, ei, data, rankE, rankV, seg,
                                          bhE, bhV, pair, nnz, m, epb);

    gather_y_linear<<<(m + 3) / 4, 256, 0, stream>>>(nfh, seg, pair, wp, b, e16, m);
    gather_out<<<(n + 3) / 4, 256, 0, stream>>>(e16, seg, pair, out, n, m, 2 * nnz);
}